// Round 1
// baseline (481.590 us; speedup 1.0000x reference)
//
#include <hip/hip_runtime.h>

typedef __attribute__((ext_vector_type(8))) short short8;
typedef __attribute__((ext_vector_type(4))) float floatx4;
typedef unsigned short u16;
typedef unsigned int u32;

#define MFMA16(a,b,c) __builtin_amdgcn_mfma_f32_16x16x32_bf16((a),(b),(c),0,0,0)

// async global->LDS, 16B/lane; LDS dest = wave-uniform base + lane*16 (linear)
#define GLD_LDS16(src, dst)                                                    \
  __builtin_amdgcn_global_load_lds(                                            \
      (const __attribute__((address_space(1))) u32*)(const u32*)(src),         \
      (__attribute__((address_space(3))) u32*)(u32*)(dst), 16, 0, 0)

// counted vmcnt wait: never drain the chunk pipeline to 0 in the steady loop
#define WAITVM(N)                                                              \
  do {                                                                         \
    asm volatile("s_waitcnt vmcnt(" #N ")" ::: "memory");                      \
    __builtin_amdgcn_sched_barrier(0);                                         \
  } while (0)

#define WAITLGKM0() asm volatile("s_waitcnt lgkmcnt(0)" ::: "memory")

// barrier that does NOT drain vmcnt (keeps global_load_lds prefetches alive)
__device__ __forceinline__ void bar_lds() {
  WAITLGKM0();                      // own ds_writes visible before barrier
  __builtin_amdgcn_s_barrier();
  asm volatile("" ::: "memory");
}

__device__ __forceinline__ u16 f2bf(float f) {
  u32 u = __builtin_bit_cast(u32, f);
  u += 0x7fffu + ((u >> 16) & 1u);   // RNE; inputs finite
  return (u16)(u >> 16);
}
__device__ __forceinline__ u32 pk2(float a, float b) {
  return (u32)f2bf(a) | ((u32)f2bf(b) << 16);
}

// ---------- batched 64x64-tile transpose, fp32 in -> bf16 out ----------
__global__ __launch_bounds__(256) void tk_f2b(const float* __restrict__ in,
                                              u16* __restrict__ out,
                                              int NI, int NJ) {
  __shared__ float tile[64][65];
  const int tid = threadIdx.x;
  const long long base = (long long)blockIdx.z * NI * NJ;
  const int i0 = blockIdx.x * 64, j0 = blockIdx.y * 64;
#pragma unroll
  for (int p = 0; p < 4; ++p) {
    int i = p * 16 + (tid >> 4);
    int jl = (tid & 15) * 4;
    float4 v = *(const float4*)(in + base + (long long)(i0 + i) * NJ + j0 + jl);
    tile[i][jl + 0] = v.x; tile[i][jl + 1] = v.y;
    tile[i][jl + 2] = v.z; tile[i][jl + 3] = v.w;
  }
  __syncthreads();
#pragma unroll
  for (int p = 0; p < 4; ++p) {
    int j = p * 16 + (tid >> 4);
    int il = (tid & 15) * 4;
    float e0 = tile[il + 0][j], e1 = tile[il + 1][j];
    float e2 = tile[il + 2][j], e3 = tile[il + 3][j];
    uint2 o; o.x = pk2(e0, e1); o.y = pk2(e2, e3);
    *(uint2*)(out + base + (long long)(j0 + j) * NI + i0 + il) = o;
  }
}

// ---------- batched 64x64-tile transpose, fp32 -> fp32 ----------
__global__ __launch_bounds__(256) void tk_f2f(const float* __restrict__ in,
                                              float* __restrict__ out,
                                              int NI, int NJ) {
  __shared__ float tile[64][65];
  const int tid = threadIdx.x;
  const long long base = (long long)blockIdx.z * NI * NJ;
  const int i0 = blockIdx.x * 64, j0 = blockIdx.y * 64;
#pragma unroll
  for (int p = 0; p < 4; ++p) {
    int i = p * 16 + (tid >> 4);
    int jl = (tid & 15) * 4;
    float4 v = *(const float4*)(in + base + (long long)(i0 + i) * NJ + j0 + jl);
    tile[i][jl + 0] = v.x; tile[i][jl + 1] = v.y;
    tile[i][jl + 2] = v.z; tile[i][jl + 3] = v.w;
  }
  __syncthreads();
#pragma unroll
  for (int p = 0; p < 4; ++p) {
    int j = p * 16 + (tid >> 4);
    int il = (tid & 15) * 4;
    float4 o;
    o.x = tile[il + 0][j]; o.y = tile[il + 1][j];
    o.z = tile[il + 2][j]; o.w = tile[il + 3][j];
    *(float4*)(out + base + (long long)(j0 + j) * NI + i0 + il) = o;
  }
}

// ---------------- fused GCN kernel: one WG per (b,m), 2 WGs/CU ----------------
// xT: [b*64+m][32 f][256 n] bf16 (ws).  Bases: [b][m][256 n][256 v] fp32.
// W: [64][224] fp32.  Output yT: [b*64+m][64 o][256 c] fp32 (ws).
// A is STREAMED (fp32) through a 3-slot LDS ring via global_load_lds with
// counted vmcnt; hop2 re-streams A (hits L2/L3: all 512 blocks co-resident).
__global__ __launch_bounds__(256, 2) void gcn_main(
    const u16* __restrict__ xT, const float* __restrict__ A0,
    const float* __restrict__ A1, const float* __restrict__ A2,
    const float* __restrict__ Wm, const float* __restrict__ bias,
    float* __restrict__ yT) {
  // LDS (80KB total -> 2 blocks/CU):
  //   ring:   3 slots x 16KB, each slot = [wave:4][16 n-rows][64 v] fp32
  //   fragX1: 16KB (x1 as A-operand frags, cross-wave)
  //   fragH:  16KB (B-operand frags for channel-mix GEMM, wave-private rows)
  __shared__ __align__(16) unsigned char smem[81920];
  unsigned char* ring   = smem;
  unsigned char* fragX1 = smem + 49152;
  unsigned char* fragH  = smem + 65536;

  const int tid  = threadIdx.x;
  const int w    = tid >> 6;       // wave id: columns 64w..64w+63
  const int lane = tid & 63;
  const int q    = lane >> 4;
  const int s    = lane & 15;
  const int wg   = blockIdx.x;     // b*64 + m

  const float* Acur  = A0 + (size_t)wg * 65536;
  const float* Anxt  = A1 + (size_t)wg * 65536;
  const float* Alast = A2 + (size_t)wg * 65536;

  // staging geometry: per wave-instr i we move 4 rows x 64 cols (1KB).
  // source col is pre-XOR-swizzled by 16 floats for rows 8..15 of a chunk so
  // the strided b32 fragment reads below are bank-conflict-free (rule 21:
  // linear LDS dest + inverse-swizzled source + swizzled read).
  const int lrow = (lane >> 4) << 8;               // (lane/16)*256 floats
  const int lc0  = (w << 6) + ((lane & 15) << 2);  // 64w + 4*(lane&15)
  const int lc1  = lc0 ^ 16;
  char* wring = (char*)ring + (w << 12);           // this wave's 4KB quadrant

  auto stage = [&](const float* Ap, int c, int slot) {
#pragma unroll
    for (int i = 0; i < 4; ++i) {
      const float* src = Ap + (c << 12) + (i << 10) + lrow + ((i & 2) ? lc1 : lc0);
      GLD_LDS16(src, wring + slot * 16384 + (i << 10));
    }
  };

  // kick off base-0 chunks 0..2 as early as possible
  stage(Acur, 0, 0);
  stage(Acur, 1, 1);
  stage(Acur, 2, 2);

  // ---- x A-operand fragments (32x256 bf16), straight from xT, in regs
  short8 xa[2][8];
  const u16* xp = xT + (size_t)wg * 8192;
#pragma unroll
  for (int mr = 0; mr < 2; ++mr)
#pragma unroll
    for (int k = 0; k < 8; ++k)
      xa[mr][k] = *(const short8*)(xp + (16 * mr + s) * 256 + 32 * k + 8 * q);

  // ---- write x into fragH (B-operand layout); rows (c>>4)=4w.. are wave-private
#pragma unroll
  for (int mr = 0; mr < 2; ++mr)
#pragma unroll
    for (int kk = 0; kk < 8; ++kk) {
      if ((kk >> 1) != w) continue;
#pragma unroll
      for (int jj = 0; jj < 8; ++jj) {
        int c = 32 * kk + 8 * q + jj;
        int f = 16 * mr + s;
        int off = (((c >> 4) * 64 + (f >> 3) * 16 + (c & 15)) << 4) + 2 * (f & 7);
        *(u16*)(fragH + off) = (u16)xa[mr][kk][jj];
      }
    }

  floatx4 yacc[4][4];
#pragma unroll
  for (int mr = 0; mr < 4; ++mr)
#pragma unroll
    for (int t = 0; t < 4; ++t) yacc[mr][t] = (floatx4){0.f, 0.f, 0.f, 0.f};

  auto finalGemm = [&](int jblk) {   // yacc += W[:, 32j:32j+32] * fragH
    short8 wf[4], hf[4];
#pragma unroll
    for (int mr = 0; mr < 4; ++mr) {
      const float* wp = Wm + (16 * mr + s) * 224 + 32 * jblk + 8 * q;
      float4 lo = *(const float4*)wp;
      float4 hi = *(const float4*)(wp + 4);
      union { uint4 u; short8 v; } r;
      r.u.x = pk2(lo.x, lo.y); r.u.y = pk2(lo.z, lo.w);
      r.u.z = pk2(hi.x, hi.y); r.u.w = pk2(hi.z, hi.w);
      wf[mr] = r.v;
    }
#pragma unroll
    for (int t = 0; t < 4; ++t)
      hf[t] = *(const short8*)(fragH + (((4 * w + t) * 64 + lane) << 4));
#pragma unroll
    for (int mr = 0; mr < 4; ++mr)
#pragma unroll
      for (int t = 0; t < 4; ++t)
        yacc[mr][t] = MFMA16(wf[mr], hf[t], yacc[mr][t]);
  };
  auto writeH = [&](const floatx4 (&acc)[2][4]) {  // C-layout acc -> B-op frags
#pragma unroll
    for (int mr = 0; mr < 2; ++mr)
#pragma unroll
      for (int t = 0; t < 4; ++t)
#pragma unroll
        for (int r = 0; r < 4; ++r) {
          int F = 16 * mr + 4 * q + r;
          int off = (((4 * w + t) * 64 + (F >> 3) * 16 + s) << 4) + 2 * (F & 7);
          *(u16*)(fragH + off) = f2bf(acc[mr][t][r]);
        }
  };
  auto writeX1 = [&](const floatx4 (&acc)[2][4]) { // C-layout acc -> A-op frags
#pragma unroll
    for (int mr = 0; mr < 2; ++mr)
#pragma unroll
      for (int t = 0; t < 4; ++t) {
        int Cc = 64 * w + 16 * t + s;
        int kk = Cc >> 5, qq = (Cc >> 3) & 3, jj = Cc & 7;
#pragma unroll
        for (int r = 0; r < 4; ++r) {
          int off = (((mr * 8 + kk) * 64 + qq * 16 + 4 * q + r) << 4) + 2 * jj;
          *(u16*)(fragX1 + off) = f2bf(acc[mr][t][r]);
        }
      }
  };

  // B-operand fragment fetch from the fp32 ring: lane(q,s) reads
  // A[32kk+8q+j][64w+16t+s], j=0..7, converting to bf16 on the fly.
  // swizzled read: pv = (16t+s) ^ ((q&1)<<4) -> 2 lanes/bank (free).
  auto fetchB = [&](int sl0, int sl1, short8 (&bf)[4]) {
    const char* bse = (const char*)ring + ((q >= 2) ? sl1 : sl0) * 16384 +
                      (w << 12) + ((q & 1) << 11);
    const int pvx = (q & 1) << 4;
#pragma unroll
    for (int t = 0; t < 4; ++t) {
      const float* fp = (const float*)(bse + ((((t << 4) + s) ^ pvx) << 2));
      union { uint4 u; short8 v; } r;
      r.u.x = pk2(fp[0],   fp[64]);
      r.u.y = pk2(fp[128], fp[192]);
      r.u.z = pk2(fp[256], fp[320]);
      r.u.w = pk2(fp[384], fp[448]);
      bf[t] = r.v;
    }
  };

  finalGemm(0);   // y += W0 * x   (fragH wave-private: no barrier needed)

#pragma unroll 1
  for (int ib = 0; ib < 3; ++ib) {
    // ---- pass 1: hop1 x1 = x*A, ring-streaming A (16 chunks of 16 rows) ----
    floatx4 h1[2][4];
#pragma unroll
    for (int mr = 0; mr < 2; ++mr)
#pragma unroll
      for (int t = 0; t < 4; ++t) h1[mr][t] = (floatx4){0.f, 0.f, 0.f, 0.f};
#pragma unroll
    for (int kk = 0; kk < 8; ++kk) {
      if (kk < 7) WAITVM(4); else WAITVM(0);
      short8 bf[4];
      fetchB((2 * kk) % 3, (2 * kk + 1) % 3, bf);
#pragma unroll
      for (int mr = 0; mr < 2; ++mr)
#pragma unroll
        for (int t = 0; t < 4; ++t)
          h1[mr][t] = MFMA16(xa[mr][kk], bf[t], h1[mr][t]);
      WAITLGKM0();   // ring reads retired before DMA may overwrite their slot
      if (kk < 6) {
        stage(Acur, 2 * kk + 3, (2 * kk + 3) % 3);
        stage(Acur, 2 * kk + 4, (2 * kk + 4) % 3);
      } else if (kk == 6) {
        stage(Acur, 15, 0);
      } else {       // pass-2 prologue: re-stream A from L2/L3
        stage(Acur, 0, 0); stage(Acur, 1, 1); stage(Acur, 2, 2);
      }
    }
    bar_lds();                       // prev base's fragX1 readers done
    writeX1(h1);
    writeH(h1);
    bar_lds();                       // fragX1 visible to all waves
    finalGemm(1 + 2 * ib);           // y += W1_i * x1

    // ---- pass 2: hop2 x2 = x1*A, ring re-streaming A ----
    floatx4 h2[2][4];
#pragma unroll
    for (int mr = 0; mr < 2; ++mr)
#pragma unroll
      for (int t = 0; t < 4; ++t) h2[mr][t] = (floatx4){0.f, 0.f, 0.f, 0.f};
#pragma unroll
    for (int kk = 0; kk < 8; ++kk) {
      if (kk < 7) WAITVM(4); else WAITVM(0);
      short8 bf[4];
      fetchB((2 * kk) % 3, (2 * kk + 1) % 3, bf);
      short8 a0 = *(const short8*)(fragX1 + ((kk * 64 + lane) << 4));
      short8 a1 = *(const short8*)(fragX1 + (((8 + kk) * 64 + lane) << 4));
#pragma unroll
      for (int t = 0; t < 4; ++t) {
        h2[0][t] = MFMA16(a0, bf[t], h2[0][t]);
        h2[1][t] = MFMA16(a1, bf[t], h2[1][t]);
      }
      WAITLGKM0();
      if (kk < 6) {
        stage(Acur, 2 * kk + 3, (2 * kk + 3) % 3);
        stage(Acur, 2 * kk + 4, (2 * kk + 4) % 3);
      } else if (kk == 6) {
        stage(Acur, 15, 0);
      } else if (ib < 2) {           // prologue of next base
        stage(Anxt, 0, 0); stage(Anxt, 1, 1); stage(Anxt, 2, 2);
      }
    }
    writeH(h2);                      // fragH wave-private: no barrier needed
    finalGemm(2 + 2 * ib);           // y += W2_i * x2

    Acur = Anxt; Anxt = Alast;
  }

  // ---- epilogue: bias + store yT[wg][o][c] (fp32)
  float* yp = yT + (size_t)wg * 16384;
#pragma unroll
  for (int mr = 0; mr < 4; ++mr) {
    float br[4];
#pragma unroll
    for (int r = 0; r < 4; ++r) br[r] = bias[16 * mr + 4 * q + r];
#pragma unroll
    for (int t = 0; t < 4; ++t) {
      int c = 64 * w + 16 * t + s;
#pragma unroll
      for (int r = 0; r < 4; ++r) {
        int o = 16 * mr + 4 * q + r;
        yp[o * 256 + c] = yacc[mr][t][r] + br[r];
      }
    }
  }
}

extern "C" void kernel_launch(void* const* d_in, const int* in_sizes, int n_in,
                              void* d_out, int out_size, void* d_ws, size_t ws_size,
                              hipStream_t stream) {
  const float* x    = (const float*)d_in[0];
  const float* b0   = (const float*)d_in[1];
  const float* b1   = (const float*)d_in[2];
  const float* b2   = (const float*)d_in[3];
  const float* Wm   = (const float*)d_in[4];
  const float* bias = (const float*)d_in[5];
  u16*   xT  = (u16*)d_ws;                          //  8 MB bf16: [b*64+m][f][n]
  float* yTs = (float*)((char*)d_ws + 8388608);     // 33.5 MB fp32: [b*64+m][o][c]
  float* out = (float*)d_out;

  // K1: x fp32 [b][f*256+n][m] -> xT bf16 [b][m][f*256+n]
  tk_f2b<<<dim3(128, 1, 8), 256, 0, stream>>>(x, xT, 8192, 64);
  // K2: fused nconv chain + channel mix (A streamed, 2 blocks/CU)
  gcn_main<<<dim3(512), 256, 0, stream>>>(xT, b0, b1, b2, Wm, bias, yTs);
  // K3: yT fp32 [b][m][o*256+c] -> y fp32 [b][o*256+c][m]
  tk_f2f<<<dim3(1, 256, 8), 256, 0, stream>>>(yTs, out, 64, 16384);
}

// Round 2
// 392.193 us; speedup vs baseline: 1.2279x; 1.2279x over previous
//
#include <hip/hip_runtime.h>

typedef __attribute__((ext_vector_type(8))) short short8;
typedef __attribute__((ext_vector_type(4))) float floatx4;
typedef unsigned short u16;
typedef unsigned int u32;

#define MFMA16(a,b,c) __builtin_amdgcn_mfma_f32_16x16x32_bf16((a),(b),(c),0,0,0)

// async global->LDS, 16B/lane; LDS dest = wave-uniform base + lane*16 (linear)
#define GLD_LDS16(src, dst)                                                    \
  __builtin_amdgcn_global_load_lds(                                            \
      (const __attribute__((address_space(1))) u32*)(const u32*)(src),         \
      (__attribute__((address_space(3))) u32*)(u32*)(dst), 16, 0, 0)

// counted vmcnt wait: never drain the chunk pipeline to 0 in the steady loop
#define WAITVM(N)                                                              \
  do {                                                                         \
    asm volatile("s_waitcnt vmcnt(" #N ")" ::: "memory");                      \
    __builtin_amdgcn_sched_barrier(0);                                         \
  } while (0)

#define WAITLGKM0() asm volatile("s_waitcnt lgkmcnt(0)" ::: "memory")

// barrier that does NOT drain vmcnt (keeps global_load_lds prefetches alive)
__device__ __forceinline__ void bar_lds() {
  WAITLGKM0();                      // own ds_writes visible before barrier
  __builtin_amdgcn_s_barrier();
  asm volatile("" ::: "memory");
}

__device__ __forceinline__ u16 f2bf(float f) {
  u32 u = __builtin_bit_cast(u32, f);
  u += 0x7fffu + ((u >> 16) & 1u);   // RNE; inputs finite
  return (u16)(u >> 16);
}
__device__ __forceinline__ u32 pk2(float a, float b) {
  return (u32)f2bf(a) | ((u32)f2bf(b) << 16);
}

// ---------- batched 64x64-tile transpose, fp32 in -> bf16 out ----------
__global__ __launch_bounds__(256) void tk_f2b(const float* __restrict__ in,
                                              u16* __restrict__ out,
                                              int NI, int NJ) {
  __shared__ float tile[64][65];
  const int tid = threadIdx.x;
  const long long base = (long long)blockIdx.z * NI * NJ;
  const int i0 = blockIdx.x * 64, j0 = blockIdx.y * 64;
#pragma unroll
  for (int p = 0; p < 4; ++p) {
    int i = p * 16 + (tid >> 4);
    int jl = (tid & 15) * 4;
    float4 v = *(const float4*)(in + base + (long long)(i0 + i) * NJ + j0 + jl);
    tile[i][jl + 0] = v.x; tile[i][jl + 1] = v.y;
    tile[i][jl + 2] = v.z; tile[i][jl + 3] = v.w;
  }
  __syncthreads();
#pragma unroll
  for (int p = 0; p < 4; ++p) {
    int j = p * 16 + (tid >> 4);
    int il = (tid & 15) * 4;
    float e0 = tile[il + 0][j], e1 = tile[il + 1][j];
    float e2 = tile[il + 2][j], e3 = tile[il + 3][j];
    uint2 o; o.x = pk2(e0, e1); o.y = pk2(e2, e3);
    *(uint2*)(out + base + (long long)(j0 + j) * NI + i0 + il) = o;
  }
}

// ---------- batched 64x64-tile transpose, fp32 -> fp32 ----------
__global__ __launch_bounds__(256) void tk_f2f(const float* __restrict__ in,
                                              float* __restrict__ out,
                                              int NI, int NJ) {
  __shared__ float tile[64][65];
  const int tid = threadIdx.x;
  const long long base = (long long)blockIdx.z * NI * NJ;
  const int i0 = blockIdx.x * 64, j0 = blockIdx.y * 64;
#pragma unroll
  for (int p = 0; p < 4; ++p) {
    int i = p * 16 + (tid >> 4);
    int jl = (tid & 15) * 4;
    float4 v = *(const float4*)(in + base + (long long)(i0 + i) * NJ + j0 + jl);
    tile[i][jl + 0] = v.x; tile[i][jl + 1] = v.y;
    tile[i][jl + 2] = v.z; tile[i][jl + 3] = v.w;
  }
  __syncthreads();
#pragma unroll
  for (int p = 0; p < 4; ++p) {
    int j = p * 16 + (tid >> 4);
    int il = (tid & 15) * 4;
    float4 o;
    o.x = tile[il + 0][j]; o.y = tile[il + 1][j];
    o.z = tile[il + 2][j]; o.w = tile[il + 3][j];
    *(float4*)(out + base + (long long)(j0 + j) * NI + i0 + il) = o;
  }
}

// ---------------- fused GCN kernel: one WG per (b,m), 1 WG/CU ----------------
// xT: [b*64+m][32 f][256 n] bf16 (ws).  Bases: [b][m][256 n][256 v] fp32.
// W: [64][224] fp32.  Output yT: [b*64+m][64 o][256 c] fp32 (ws).
// SINGLE PASS over A per base: fp32 A streams through a 4-slot LDS ring via
// global_load_lds with counted vmcnt; pass-1 fetchB converts to bf16 B-frags
// consumed by hop1 AND persisted in registers (afrag[8][4], 128 VGPR) so hop2
// needs NO second read of A. W is pre-packed to LDS so the in-loop vmcnt
// counters see only ring DMAs.
__global__ __launch_bounds__(256, 1) void gcn_main(
    const u16* __restrict__ xT, const float* __restrict__ A0,
    const float* __restrict__ A1, const float* __restrict__ A2,
    const float* __restrict__ Wm, const float* __restrict__ bias,
    float* __restrict__ yT) {
  // LDS (124KB):
  //   ring:   4 slots x 16KB fp32 chunks (16 n-rows x 256 v each)
  //   fragX1: 16KB (x1 as A-operand frags, cross-wave)
  //   fragH:  16KB (B-operand frags for channel-mix GEMM, wave-private rows)
  //   wLds:   28KB (W pre-packed bf16 A-operand frags, 7 jblk x 4 mr)
  __shared__ __align__(16) unsigned char smem[126976];
  unsigned char* ring   = smem;
  unsigned char* fragX1 = smem + 65536;
  unsigned char* fragH  = smem + 81920;
  unsigned char* wLds   = smem + 98304;

  const int tid  = threadIdx.x;
  const int w    = tid >> 6;       // wave id: columns 64w..64w+63
  const int lane = tid & 63;
  const int q    = lane >> 4;
  const int s    = lane & 15;
  const int wg   = blockIdx.x;     // b*64 + m

  const float* Acur  = A0 + (size_t)wg * 65536;
  const float* Anxt  = A1 + (size_t)wg * 65536;
  const float* Alast = A2 + (size_t)wg * 65536;

  // staging geometry: per wave-instr i we move 4 rows x 64 cols (1KB).
  // source col pre-XOR-swizzled by 16 floats for rows 8..15 of a chunk so the
  // strided b32 fragment reads are ~conflict-free (rule 21: linear LDS dest +
  // inverse-swizzled source + swizzled read).
  const int lrow = (lane >> 4) << 8;               // (lane/16)*256 floats
  const int lc0  = (w << 6) + ((lane & 15) << 2);  // 64w + 4*(lane&15)
  const int lc1  = lc0 ^ 16;
  char* wring = (char*)ring + (w << 12);           // this wave's 4KB quadrant

  auto stage = [&](const float* Ap, int c, int slot) {
#pragma unroll
    for (int i = 0; i < 4; ++i) {
      const float* src = Ap + (c << 12) + (i << 10) + lrow + ((i & 2) ? lc1 : lc0);
      GLD_LDS16(src, wring + slot * 16384 + (i << 10));
    }
  };

  // prologue: chunks 0..3 of base 0 in flight ASAP
  stage(Acur, 0, 0);
  stage(Acur, 1, 1);
  stage(Acur, 2, 2);
  stage(Acur, 3, 3);

  // ---- W -> LDS as pre-packed bf16 A-operand fragments (once) ----
  // fragment (jblk, mr, lane) = bf16 of W[16mr+s][32jblk+8q .. +8]
#pragma unroll 2
  for (int jb = w; jb < 7; jb += 4)
#pragma unroll
    for (int mr = 0; mr < 4; ++mr) {
      const float* wp = Wm + (16 * mr + s) * 224 + 32 * jb + 8 * q;
      float4 lo = *(const float4*)wp;
      float4 hi = *(const float4*)(wp + 4);
      uint4 r;
      r.x = pk2(lo.x, lo.y); r.y = pk2(lo.z, lo.w);
      r.z = pk2(hi.x, hi.y); r.w = pk2(hi.z, hi.w);
      *(uint4*)(wLds + (((jb * 4 + mr) * 64 + lane) << 4)) = r;
    }

  // ---- x A-operand fragments (32x256 bf16), straight from xT, in regs
  short8 xa[2][8];
  const u16* xp = xT + (size_t)wg * 8192;
#pragma unroll
  for (int mr = 0; mr < 2; ++mr)
#pragma unroll
    for (int k = 0; k < 8; ++k)
      xa[mr][k] = *(const short8*)(xp + (16 * mr + s) * 256 + 32 * k + 8 * q);

  // ---- write x into fragH (B-operand layout); rows (c>>4)=4w.. wave-private
#pragma unroll
  for (int mr = 0; mr < 2; ++mr)
#pragma unroll
    for (int kk = 0; kk < 8; ++kk) {
      if ((kk >> 1) != w) continue;
#pragma unroll
      for (int jj = 0; jj < 8; ++jj) {
        int c = 32 * kk + 8 * q + jj;
        int f = 16 * mr + s;
        int off = (((c >> 4) * 64 + (f >> 3) * 16 + (c & 15)) << 4) + 2 * (f & 7);
        *(u16*)(fragH + off) = (u16)xa[mr][kk][jj];
      }
    }

  floatx4 yacc[4][4];
#pragma unroll
  for (int mr = 0; mr < 4; ++mr)
#pragma unroll
    for (int t = 0; t < 4; ++t) yacc[mr][t] = (floatx4){0.f, 0.f, 0.f, 0.f};

  auto finalGemm = [&](int jblk) {   // yacc += W[:, 32j:32j+32] * fragH
    short8 wf[4], hf[4];
#pragma unroll
    for (int mr = 0; mr < 4; ++mr)
      wf[mr] = *(const short8*)(wLds + (((jblk * 4 + mr) * 64 + lane) << 4));
#pragma unroll
    for (int t = 0; t < 4; ++t)
      hf[t] = *(const short8*)(fragH + (((4 * w + t) * 64 + lane) << 4));
#pragma unroll
    for (int mr = 0; mr < 4; ++mr)
#pragma unroll
      for (int t = 0; t < 4; ++t)
        yacc[mr][t] = MFMA16(wf[mr], hf[t], yacc[mr][t]);
  };
  auto writeH = [&](const floatx4 (&acc)[2][4]) {  // C-layout acc -> B-op frags
#pragma unroll
    for (int mr = 0; mr < 2; ++mr)
#pragma unroll
      for (int t = 0; t < 4; ++t)
#pragma unroll
        for (int r = 0; r < 4; ++r) {
          int F = 16 * mr + 4 * q + r;
          int off = (((4 * w + t) * 64 + (F >> 3) * 16 + s) << 4) + 2 * (F & 7);
          *(u16*)(fragH + off) = f2bf(acc[mr][t][r]);
        }
  };
  auto writeX1 = [&](const floatx4 (&acc)[2][4]) { // C-layout acc -> A-op frags
#pragma unroll
    for (int mr = 0; mr < 2; ++mr)
#pragma unroll
      for (int t = 0; t < 4; ++t) {
        int Cc = 64 * w + 16 * t + s;
        int kk = Cc >> 5, qq = (Cc >> 3) & 3, jj = Cc & 7;
#pragma unroll
        for (int r = 0; r < 4; ++r) {
          int off = (((mr * 8 + kk) * 64 + qq * 16 + 4 * q + r) << 4) + 2 * jj;
          *(u16*)(fragX1 + off) = f2bf(acc[mr][t][r]);
        }
      }
  };

  // B-operand fragment fetch from the fp32 ring: lane(q,s) reads
  // A[32kk+8q+j][64w+16t+s], j=0..7, converting to bf16 on the fly.
  auto fetchB = [&](int sl0, int sl1, short8 (&bf)[4]) {
    const char* bse = (const char*)ring + ((q >= 2) ? sl1 : sl0) * 16384 +
                      (w << 12) + ((q & 1) << 11);
    const int pvx = (q & 1) << 4;
#pragma unroll
    for (int t = 0; t < 4; ++t) {
      const float* fp = (const float*)(bse + ((((t << 4) + s) ^ pvx) << 2));
      union { uint4 u; short8 v; } r;
      r.u.x = pk2(fp[0],   fp[64]);
      r.u.y = pk2(fp[128], fp[192]);
      r.u.z = pk2(fp[256], fp[320]);
      r.u.w = pk2(fp[384], fp[448]);
      bf[t] = r.v;
    }
  };

  bar_lds();      // wLds visible to all waves (does NOT drain vmcnt)
  finalGemm(0);   // y += W0 * x   (fragH rows wave-private)

  // persisted A fragments for hop2: wave w keeps (k, tg=4w+t) for all k
  short8 afrag[8][4];

#pragma unroll 1
  for (int ib = 0; ib < 3; ++ib) {
    // ---- pass 1 (the ONLY pass over A): hop1 x1 = x*A, ring-streaming ----
    floatx4 h1[2][4];
#pragma unroll
    for (int mr = 0; mr < 2; ++mr)
#pragma unroll
      for (int t = 0; t < 4; ++t) h1[mr][t] = (floatx4){0.f, 0.f, 0.f, 0.f};
#pragma unroll
    for (int kk = 0; kk < 8; ++kk) {
      // steady state: 4 chunks (16 GLD/wave) outstanding; wait for oldest 2
      if (kk == 7) {
        if (ib == 2) WAITVM(0); else WAITVM(8);
      } else {
        WAITVM(8);
      }
      fetchB((2 * kk) & 3, (2 * kk + 1) & 3, afrag[kk]);
      WAITLGKM0();   // ring reads retired before DMA may overwrite their slot
      {
        const int cn = 2 * kk + 4;           // chunks consumed at kk+2
        if (cn < 16) {
          stage(Acur, cn, cn & 3);
          stage(Acur, cn + 1, (cn + 1) & 3);
        } else if (ib < 2) {                 // prologue of next base
          stage(Anxt, cn - 16, (cn - 16) & 3);
          stage(Anxt, cn - 15, (cn - 15) & 3);
        }
      }
#pragma unroll
      for (int mr = 0; mr < 2; ++mr)
#pragma unroll
        for (int t = 0; t < 4; ++t)
          h1[mr][t] = MFMA16(xa[mr][kk], afrag[kk][t], h1[mr][t]);
    }
    bar_lds();                       // prev base's fragX1 readers done
    writeX1(h1);
    writeH(h1);
    bar_lds();                       // fragX1 visible to all waves
    finalGemm(1 + 2 * ib);           // y += W1_i * x1

    // ---- hop2: x2 = x1*A, A entirely from registers (afrag) ----
    floatx4 h2[2][4];
#pragma unroll
    for (int mr = 0; mr < 2; ++mr)
#pragma unroll
      for (int t = 0; t < 4; ++t) h2[mr][t] = (floatx4){0.f, 0.f, 0.f, 0.f};
#pragma unroll
    for (int kk = 0; kk < 8; ++kk) {
      short8 a0 = *(const short8*)(fragX1 + ((kk * 64 + lane) << 4));
      short8 a1 = *(const short8*)(fragX1 + (((8 + kk) * 64 + lane) << 4));
#pragma unroll
      for (int t = 0; t < 4; ++t) {
        h2[0][t] = MFMA16(a0, afrag[kk][t], h2[0][t]);
        h2[1][t] = MFMA16(a1, afrag[kk][t], h2[1][t]);
      }
    }
    writeH(h2);                      // fragH wave-private: no barrier needed
    finalGemm(2 + 2 * ib);           // y += W2_i * x2

    Acur = Anxt; Anxt = Alast;
  }

  // ---- epilogue: bias + store yT[wg][o][c] (fp32)
  float* yp = yT + (size_t)wg * 16384;
#pragma unroll
  for (int mr = 0; mr < 4; ++mr) {
    float br[4];
#pragma unroll
    for (int r = 0; r < 4; ++r) br[r] = bias[16 * mr + 4 * q + r];
#pragma unroll
    for (int t = 0; t < 4; ++t) {
      int c = 64 * w + 16 * t + s;
#pragma unroll
      for (int r = 0; r < 4; ++r) {
        int o = 16 * mr + 4 * q + r;
        yp[o * 256 + c] = yacc[mr][t][r] + br[r];
      }
    }
  }
}

extern "C" void kernel_launch(void* const* d_in, const int* in_sizes, int n_in,
                              void* d_out, int out_size, void* d_ws, size_t ws_size,
                              hipStream_t stream) {
  const float* x    = (const float*)d_in[0];
  const float* b0   = (const float*)d_in[1];
  const float* b1   = (const float*)d_in[2];
  const float* b2   = (const float*)d_in[3];
  const float* Wm   = (const float*)d_in[4];
  const float* bias = (const float*)d_in[5];
  u16*   xT  = (u16*)d_ws;                          //  8 MB bf16: [b*64+m][f][n]
  float* yTs = (float*)((char*)d_ws + 8388608);     // 33.5 MB fp32: [b*64+m][o][c]
  float* out = (float*)d_out;

  // K1: x fp32 [b][f*256+n][m] -> xT bf16 [b][m][f*256+n]
  tk_f2b<<<dim3(128, 1, 8), 256, 0, stream>>>(x, xT, 8192, 64);
  // K2: fused nconv chain + channel mix (A streamed ONCE, hop2 from regs)
  gcn_main<<<dim3(512), 256, 0, stream>>>(xT, b0, b1, b2, Wm, bias, yTs);
  // K3: yT fp32 [b][m][o*256+c] -> y fp32 [b][o*256+c][m]
  tk_f2f<<<dim3(1, 256, 8), 256, 0, stream>>>(yTs, out, 64, 16384);
}